// Round 8
// baseline (239.380 us; speedup 1.0000x reference)
//
#include <hip/hip_runtime.h>
#include <hip/hip_bf16.h>
#include <math.h>

// Problem constants: N=3072 nodes, F=128 in-feats, H=16 hidden, O=8 out
#define NN 3072
#define FF 128
#define HH 16
#define OO 8

#define SCH  4                 // m-chunks per row
#define MC   (NN / SCH)        // 768 m per chunk
#define WPB  4                 // waves per block (256 threads)

// ws layout (float offsets): gT[O][N] only
#define OFF_GT   0

// ---------------------------------------------------------------------------
// Kernel 1: gT[o][n] = sum_f ( sum_h relu(x[n,f]*W1[f,h]+b1[f,h]) * W2[f,h,o]
//                              + b2[f,o] )
// Thread = feature, weights streamed per-h. First 48 blocks also zero out[]
// (stream order guarantees completion before the main kernel).
// ---------------------------------------------------------------------------
#define NPB 4

__global__ __launch_bounds__(128) void gnan_g_kernel(
    const float* __restrict__ x,    // [N,F]
    const float* __restrict__ W1,   // [F,H]
    const float* __restrict__ b1,   // [F,H]
    const float* __restrict__ W2,   // [F,H,O]
    const float* __restrict__ b2,   // [F,O]
    float* __restrict__ gT,         // [O][N] in ws
    float* __restrict__ out)        // [N,O] zeroed here
{
    const int f  = threadIdx.x;
    const int n0 = blockIdx.x * NPB;

    {   // zero out[]: NN*OO = 24576 floats = 6144 float4
        const int gid = blockIdx.x * 128 + threadIdx.x;
        if (gid < NN * OO / 4)
            reinterpret_cast<float4*>(out)[gid] = make_float4(0.f, 0.f, 0.f, 0.f);
    }

    float xv[NPB];
#pragma unroll
    for (int ni = 0; ni < NPB; ++ni)
        xv[ni] = x[(size_t)(n0 + ni) * FF + f];

    const float4 b2a = *reinterpret_cast<const float4*>(b2 + f * OO);
    const float4 b2b = *reinterpret_cast<const float4*>(b2 + f * OO + 4);

    float acc[NPB][OO];
#pragma unroll
    for (int ni = 0; ni < NPB; ++ni) {
        acc[ni][0] = b2a.x; acc[ni][1] = b2a.y; acc[ni][2] = b2a.z; acc[ni][3] = b2a.w;
        acc[ni][4] = b2b.x; acc[ni][5] = b2b.y; acc[ni][6] = b2b.z; acc[ni][7] = b2b.w;
    }

    for (int h = 0; h < HH; ++h) {
        const float w1h = W1[f * HH + h];
        const float b1h = b1[f * HH + h];
        const float4 wa = *reinterpret_cast<const float4*>(W2 + (size_t)(f * HH + h) * OO);
        const float4 wb = *reinterpret_cast<const float4*>(W2 + (size_t)(f * HH + h) * OO + 4);
#pragma unroll
        for (int ni = 0; ni < NPB; ++ni) {
            const float a = fmaxf(fmaf(xv[ni], w1h, b1h), 0.f);
            acc[ni][0] = fmaf(a, wa.x, acc[ni][0]);
            acc[ni][1] = fmaf(a, wa.y, acc[ni][1]);
            acc[ni][2] = fmaf(a, wa.z, acc[ni][2]);
            acc[ni][3] = fmaf(a, wa.w, acc[ni][3]);
            acc[ni][4] = fmaf(a, wb.x, acc[ni][4]);
            acc[ni][5] = fmaf(a, wb.y, acc[ni][5]);
            acc[ni][6] = fmaf(a, wb.z, acc[ni][6]);
            acc[ni][7] = fmaf(a, wb.w, acc[ni][7]);
        }
    }

    __shared__ float wsum[NPB][2][OO];
    const int lane = threadIdx.x & 63;
    const int wid  = threadIdx.x >> 6;
#pragma unroll
    for (int ni = 0; ni < NPB; ++ni) {
#pragma unroll
        for (int o = 0; o < OO; ++o) {
#pragma unroll
            for (int off = 32; off > 0; off >>= 1)
                acc[ni][o] += __shfl_down(acc[ni][o], off);
        }
        if (lane == 0) {
#pragma unroll
            for (int o = 0; o < OO; ++o) wsum[ni][wid][o] = acc[ni][o];
        }
    }
    __syncthreads();
    if (threadIdx.x < NPB * OO) {
        const int ni = threadIdx.x >> 3, o = threadIdx.x & 7;
        gT[o * NN + (n0 + ni)] = wsum[ni][0][o] + wsum[ni][1][o];
    }
}

// ---------------------------------------------------------------------------
// Per-element accumulate. Hot path: sg += g, dg += d*g (branch never fires
// for d inside the reference interval; exact correction otherwise).
// ---------------------------------------------------------------------------
__device__ __forceinline__ void accum_one(
    float d, float clo, float chi, const float gk[OO],
    float dg[OO], float sg[OO], float corr[OO],
    const float* KpS, const float (*rowsS)[16], const float* refB)
{
#pragma unroll
    for (int o = 0; o < OO; ++o) sg[o] += gk[o];     // row-indep beta term
    if (d >= clo && d < chi) {                        // reference interval (hot)
#pragma unroll
        for (int o = 0; o < OO; ++o) dg[o] = fmaf(d, gk[o], dg[o]);
    } else {                                          // rare exact correction
        int j = 0;
#pragma unroll
        for (int p = 0; p < HH; ++p) j += (d >= KpS[1 + p]) ? 1 : 0;
#pragma unroll
        for (int o = 0; o < OO; ++o) {
            const float v = fmaf(rowsS[j][o], d, rowsS[j][8 + o]) - refB[o];
            corr[o] = fmaf(v, gk[o], corr[o]);
        }
    }
}

// ---------------------------------------------------------------------------
// Kernel 2 (main): out[n,o] += alpha_ref[o]*sum_m d*g + beta_ref[o]*sum_m g
//                              + corrections, accumulated per m-chunk.
// Grid = 3072 blocks (768 row-groups x 4 m-chunks) -> 12 blocks/CU
// oversubscribed; occupancy VGPR-bound, not grid-bound (round-7 fix).
// Wave = one row x one 768-m chunk = 3 float4 iterations.
// ---------------------------------------------------------------------------
__global__ __launch_bounds__(256, 4) void gnan_main_kernel(
    const float* __restrict__ nd,    // [N,N]
    const float* __restrict__ nm,    // [N,N]
    const float* __restrict__ gT,    // [O][N] in ws (L2-resident)
    const float* __restrict__ rW1,   // [H]
    const float* __restrict__ rb1,   // [H]
    const float* __restrict__ rW2,   // [H,O]
    const float* __restrict__ rb2,   // [O]
    float* __restrict__ out)         // [N,O], zeroed by g-kernel
{
    __shared__ float KpS[HH + 2];
    __shared__ float rowsS[HH + 1][16];
    __shared__ float refS[18];       // clo, chi, alpha_ref[8], beta_ref[8]

    const int t = threadIdx.x;

    // ---- per-block table build (parallel, sort-free; 138 threads)
    if (t < (HH + 1) * OO + 2) {
        float w[HH], bb[HH], knee[HH];
#pragma unroll
        for (int h = 0; h < HH; ++h) {
            w[h]  = rW1[h];
            bb[h] = rb1[h];
            knee[h] = (w[h] != 0.f) ? (-bb[h] / w[h]) : INFINITY;
        }
        if (t >= (HH + 1) * OO) {           // 2 threads: Kp endpoints
            KpS[(t - (HH + 1) * OO) * (HH + 1)] =
                (t == (HH + 1) * OO) ? -INFINITY : INFINITY;
        } else {
            const int j = t >> 3, o = t & 7;
            if (o == 0 && j < HH) {          // 16 threads scatter knees by rank
                int r = 0;
#pragma unroll
                for (int h2 = 0; h2 < HH; ++h2)
                    r += (knee[h2] < knee[j] || (knee[h2] == knee[j] && h2 < j)) ? 1 : 0;
                KpS[1 + r] = knee[j];
            }
            float cAdd = rb2[o];
#pragma unroll
            for (int h = 0; h < HH; ++h)
                if (w[h] == 0.f) cAdd += fmaxf(bb[h], 0.f) * rW2[h * OO + o];

            float alpha = 0.f, beta = 0.f;
#pragma unroll
            for (int h = 0; h < HH; ++h) {
                int r = 0;
#pragma unroll
                for (int h2 = 0; h2 < HH; ++h2)
                    r += (knee[h2] < knee[h] || (knee[h2] == knee[h] && h2 < h)) ? 1 : 0;
                const bool active = (w[h] > 0.f) ? (r < j)
                                  : (w[h] < 0.f ? (r >= j) : false);
                if (active) {
                    alpha += w[h]  * rW2[h * OO + o];
                    beta  += bb[h] * rW2[h * OO + o];
                }
            }
            const float betaF = beta + cAdd;
            rowsS[j][o]     = alpha;
            rowsS[j][8 + o] = betaF;

            const float d00 = nd[0] / nm[0];
            int j0 = 0;
#pragma unroll
            for (int h = 0; h < HH; ++h) j0 += (d00 >= knee[h]) ? 1 : 0;
            if (j == j0) {
                refS[2 + o]  = alpha;
                refS[10 + o] = betaF;
                if (o == 0) {
                    float clo = -INFINITY, chi = INFINITY;
#pragma unroll
                    for (int h = 0; h < HH; ++h) {
                        if (d00 >= knee[h]) clo = fmaxf(clo, knee[h]);
                        else                chi = fminf(chi, knee[h]);
                    }
                    refS[0] = clo;
                    refS[1] = chi;
                }
            }
        }
    }
    __syncthreads();

    const int wave = t >> 6;
    const int lane = t & 63;
    const int b    = blockIdx.x;
    const int rg   = b >> 2;             // row group (768)
    const int c    = b & 3;              // m chunk (4)
    const int row  = rg * WPB + wave;
    const int mb   = c * MC;

    const float clo = refS[0];
    const float chi = refS[1];
    const float* refB = &refS[10];

    const float* __restrict__ drow = nd + (size_t)row * NN + mb;
    const float* __restrict__ nrow = nm + (size_t)row * NN + mb;

    float dg[OO], sg[OO], corr[OO];
#pragma unroll
    for (int o = 0; o < OO; ++o) { dg[o] = 0.f; sg[o] = 0.f; corr[o] = 0.f; }

#pragma unroll
    for (int it = 0; it < MC / 256; ++it) {     // 3 iters, 4 m per lane
        const int m0 = it * 256 + lane * 4;
        const float4 dv = *reinterpret_cast<const float4*>(drow + m0);
        const float4 nv = *reinterpret_cast<const float4*>(nrow + m0);
        float4 gv[OO];
#pragma unroll
        for (int o = 0; o < OO; ++o)
            gv[o] = *reinterpret_cast<const float4*>(&gT[o * NN + mb + m0]);

        {
            float gk[OO];
#pragma unroll
            for (int o = 0; o < OO; ++o) gk[o] = gv[o].x;
            accum_one(__fdividef(dv.x, nv.x), clo, chi, gk, dg, sg, corr, KpS, rowsS, refB);
        }
        {
            float gk[OO];
#pragma unroll
            for (int o = 0; o < OO; ++o) gk[o] = gv[o].y;
            accum_one(__fdividef(dv.y, nv.y), clo, chi, gk, dg, sg, corr, KpS, rowsS, refB);
        }
        {
            float gk[OO];
#pragma unroll
            for (int o = 0; o < OO; ++o) gk[o] = gv[o].z;
            accum_one(__fdividef(dv.z, nv.z), clo, chi, gk, dg, sg, corr, KpS, rowsS, refB);
        }
        {
            float gk[OO];
#pragma unroll
            for (int o = 0; o < OO; ++o) gk[o] = gv[o].w;
            accum_one(__fdividef(dv.w, nv.w), clo, chi, gk, dg, sg, corr, KpS, rowsS, refB);
        }
    }

    // val[o] = alpha_ref*dg + beta_ref*sg + corr; wave-reduce; atomic add
    float val[OO];
#pragma unroll
    for (int o = 0; o < OO; ++o)
        val[o] = fmaf(refS[2 + o], dg[o], fmaf(refB[o], sg[o], corr[o]));
#pragma unroll
    for (int o = 0; o < OO; ++o) {
#pragma unroll
        for (int off = 32; off > 0; off >>= 1)
            val[o] += __shfl_down(val[o], off);
    }
    if (lane == 0) {
#pragma unroll
        for (int o = 0; o < OO; ++o)
            atomicAdd(out + (size_t)row * OO + o, val[o]);
    }
}

// ---------------------------------------------------------------------------
// Host launcher — 2 dispatches.
// Inputs: 0:x 1:edge_index(unused) 2:nd 3:nm 4:W1 5:b1 6:W2 7:b2
//         8:rW1 9:rb1 10:rW2 11:rb2
// ---------------------------------------------------------------------------
extern "C" void kernel_launch(void* const* d_in, const int* in_sizes, int n_in,
                              void* d_out, int out_size, void* d_ws, size_t ws_size,
                              hipStream_t stream) {
    const float* x   = (const float*)d_in[0];
    const float* nd  = (const float*)d_in[2];
    const float* nm  = (const float*)d_in[3];
    const float* W1  = (const float*)d_in[4];
    const float* b1  = (const float*)d_in[5];
    const float* W2  = (const float*)d_in[6];
    const float* b2  = (const float*)d_in[7];
    const float* rW1 = (const float*)d_in[8];
    const float* rb1 = (const float*)d_in[9];
    const float* rW2 = (const float*)d_in[10];
    const float* rb2 = (const float*)d_in[11];
    float* out = (float*)d_out;
    float* wsf = (float*)d_ws;

    gnan_g_kernel<<<NN / NPB, 128, 0, stream>>>(x, W1, b1, W2, b2,
                                                wsf + OFF_GT, out);
    gnan_main_kernel<<<(NN / WPB) * SCH, 256, 0, stream>>>(
        nd, nm, wsf + OFF_GT, rW1, rb1, rW2, rb2, out);
}

// Round 9
// 174.594 us; speedup vs baseline: 1.3711x; 1.3711x over previous
//
#include <hip/hip_runtime.h>
#include <hip/hip_bf16.h>
#include <math.h>

// Problem constants: N=3072 nodes, F=128 in-feats, H=16 hidden, O=8 out
#define NN 3072
#define FF 128
#define HH 16
#define OO 8

#define SCH  4                 // m-chunks per row
#define MC   (NN / SCH)        // 768 m per chunk
#define WPB  4                 // waves per block (256 threads)

// ws layout (float offsets): gT[O][N] only
#define OFF_GT   0

// ---------------------------------------------------------------------------
// Kernel 1: gT[o][n] = sum_f ( sum_h relu(x[n,f]*W1[f,h]+b1[f,h]) * W2[f,h,o]
//                              + b2[f,o] )
// Thread = feature, weights streamed per-h. First 48 blocks also zero out[]
// (stream order guarantees completion before the main kernel).
// ---------------------------------------------------------------------------
#define NPB 4

__global__ __launch_bounds__(128) void gnan_g_kernel(
    const float* __restrict__ x,    // [N,F]
    const float* __restrict__ W1,   // [F,H]
    const float* __restrict__ b1,   // [F,H]
    const float* __restrict__ W2,   // [F,H,O]
    const float* __restrict__ b2,   // [F,O]
    float* __restrict__ gT,         // [O][N] in ws
    float* __restrict__ out)        // [N,O] zeroed here
{
    const int f  = threadIdx.x;
    const int n0 = blockIdx.x * NPB;

    {   // zero out[]: NN*OO = 24576 floats = 6144 float4
        const int gid = blockIdx.x * 128 + threadIdx.x;
        if (gid < NN * OO / 4)
            reinterpret_cast<float4*>(out)[gid] = make_float4(0.f, 0.f, 0.f, 0.f);
    }

    float xv[NPB];
#pragma unroll
    for (int ni = 0; ni < NPB; ++ni)
        xv[ni] = x[(size_t)(n0 + ni) * FF + f];

    const float4 b2a = *reinterpret_cast<const float4*>(b2 + f * OO);
    const float4 b2b = *reinterpret_cast<const float4*>(b2 + f * OO + 4);

    float acc[NPB][OO];
#pragma unroll
    for (int ni = 0; ni < NPB; ++ni) {
        acc[ni][0] = b2a.x; acc[ni][1] = b2a.y; acc[ni][2] = b2a.z; acc[ni][3] = b2a.w;
        acc[ni][4] = b2b.x; acc[ni][5] = b2b.y; acc[ni][6] = b2b.z; acc[ni][7] = b2b.w;
    }

    for (int h = 0; h < HH; ++h) {
        const float w1h = W1[f * HH + h];
        const float b1h = b1[f * HH + h];
        const float4 wa = *reinterpret_cast<const float4*>(W2 + (size_t)(f * HH + h) * OO);
        const float4 wb = *reinterpret_cast<const float4*>(W2 + (size_t)(f * HH + h) * OO + 4);
#pragma unroll
        for (int ni = 0; ni < NPB; ++ni) {
            const float a = fmaxf(fmaf(xv[ni], w1h, b1h), 0.f);
            acc[ni][0] = fmaf(a, wa.x, acc[ni][0]);
            acc[ni][1] = fmaf(a, wa.y, acc[ni][1]);
            acc[ni][2] = fmaf(a, wa.z, acc[ni][2]);
            acc[ni][3] = fmaf(a, wa.w, acc[ni][3]);
            acc[ni][4] = fmaf(a, wb.x, acc[ni][4]);
            acc[ni][5] = fmaf(a, wb.y, acc[ni][5]);
            acc[ni][6] = fmaf(a, wb.z, acc[ni][6]);
            acc[ni][7] = fmaf(a, wb.w, acc[ni][7]);
        }
    }

    __shared__ float wsum[NPB][2][OO];
    const int lane = threadIdx.x & 63;
    const int wid  = threadIdx.x >> 6;
#pragma unroll
    for (int ni = 0; ni < NPB; ++ni) {
#pragma unroll
        for (int o = 0; o < OO; ++o) {
#pragma unroll
            for (int off = 32; off > 0; off >>= 1)
                acc[ni][o] += __shfl_down(acc[ni][o], off);
        }
        if (lane == 0) {
#pragma unroll
            for (int o = 0; o < OO; ++o) wsum[ni][wid][o] = acc[ni][o];
        }
    }
    __syncthreads();
    if (threadIdx.x < NPB * OO) {
        const int ni = threadIdx.x >> 3, o = threadIdx.x & 7;
        gT[o * NN + (n0 + ni)] = wsum[ni][0][o] + wsum[ni][1][o];
    }
}

// ---------------------------------------------------------------------------
// Per-element accumulate. Hot path: sg += g, dg += d*g (branch never fires
// for d inside the reference interval; exact correction otherwise).
// ---------------------------------------------------------------------------
__device__ __forceinline__ void accum_one(
    float d, float clo, float chi, const float gk[OO],
    float dg[OO], float sg[OO], float corr[OO],
    const float* KpS, const float (*rowsS)[16], const float* refB)
{
#pragma unroll
    for (int o = 0; o < OO; ++o) sg[o] += gk[o];     // row-indep beta term
    if (d >= clo && d < chi) {                        // reference interval (hot)
#pragma unroll
        for (int o = 0; o < OO; ++o) dg[o] = fmaf(d, gk[o], dg[o]);
    } else {                                          // rare exact correction
        int j = 0;
#pragma unroll
        for (int p = 0; p < HH; ++p) j += (d >= KpS[1 + p]) ? 1 : 0;
#pragma unroll
        for (int o = 0; o < OO; ++o) {
            const float v = fmaf(rowsS[j][o], d, rowsS[j][8 + o]) - refB[o];
            corr[o] = fmaf(v, gk[o], corr[o]);
        }
    }
}

// ---------------------------------------------------------------------------
// Kernel 2 (main): out[n,o] += alpha_ref[o]*sum_m d*g + beta_ref[o]*sum_m g
//                              + corrections, accumulated per m-chunk.
// Grid = 3072 blocks (768 row-groups x 4 m-chunks) -> 12 blocks/CU
// oversubscribed. ROLLED m-loop + plain launch_bounds(256): round-8's
// forced unroll + (256,4) cap caused scratch spill (WRITE_SIZE 130 MB).
// ---------------------------------------------------------------------------
__global__ __launch_bounds__(256) void gnan_main_kernel(
    const float* __restrict__ nd,    // [N,N]
    const float* __restrict__ nm,    // [N,N]
    const float* __restrict__ gT,    // [O][N] in ws (L2-resident)
    const float* __restrict__ rW1,   // [H]
    const float* __restrict__ rb1,   // [H]
    const float* __restrict__ rW2,   // [H,O]
    const float* __restrict__ rb2,   // [O]
    float* __restrict__ out)         // [N,O], zeroed by g-kernel
{
    __shared__ float KpS[HH + 2];
    __shared__ float rowsS[HH + 1][16];
    __shared__ float refS[18];       // clo, chi, alpha_ref[8], beta_ref[8]

    const int t = threadIdx.x;

    // ---- per-block table build (parallel, sort-free; 138 threads)
    if (t < (HH + 1) * OO + 2) {
        float w[HH], bb[HH], knee[HH];
#pragma unroll
        for (int h = 0; h < HH; ++h) {
            w[h]  = rW1[h];
            bb[h] = rb1[h];
            knee[h] = (w[h] != 0.f) ? (-bb[h] / w[h]) : INFINITY;
        }
        if (t >= (HH + 1) * OO) {           // 2 threads: Kp endpoints
            KpS[(t - (HH + 1) * OO) * (HH + 1)] =
                (t == (HH + 1) * OO) ? -INFINITY : INFINITY;
        } else {
            const int j = t >> 3, o = t & 7;
            if (o == 0 && j < HH) {          // 16 threads scatter knees by rank
                int r = 0;
#pragma unroll
                for (int h2 = 0; h2 < HH; ++h2)
                    r += (knee[h2] < knee[j] || (knee[h2] == knee[j] && h2 < j)) ? 1 : 0;
                KpS[1 + r] = knee[j];
            }
            float cAdd = rb2[o];
#pragma unroll
            for (int h = 0; h < HH; ++h)
                if (w[h] == 0.f) cAdd += fmaxf(bb[h], 0.f) * rW2[h * OO + o];

            float alpha = 0.f, beta = 0.f;
#pragma unroll
            for (int h = 0; h < HH; ++h) {
                int r = 0;
#pragma unroll
                for (int h2 = 0; h2 < HH; ++h2)
                    r += (knee[h2] < knee[h] || (knee[h2] == knee[h] && h2 < h)) ? 1 : 0;
                const bool active = (w[h] > 0.f) ? (r < j)
                                  : (w[h] < 0.f ? (r >= j) : false);
                if (active) {
                    alpha += w[h]  * rW2[h * OO + o];
                    beta  += bb[h] * rW2[h * OO + o];
                }
            }
            const float betaF = beta + cAdd;
            rowsS[j][o]     = alpha;
            rowsS[j][8 + o] = betaF;

            const float d00 = nd[0] / nm[0];
            int j0 = 0;
#pragma unroll
            for (int h = 0; h < HH; ++h) j0 += (d00 >= knee[h]) ? 1 : 0;
            if (j == j0) {
                refS[2 + o]  = alpha;
                refS[10 + o] = betaF;
                if (o == 0) {
                    float clo = -INFINITY, chi = INFINITY;
#pragma unroll
                    for (int h = 0; h < HH; ++h) {
                        if (d00 >= knee[h]) clo = fmaxf(clo, knee[h]);
                        else                chi = fminf(chi, knee[h]);
                    }
                    refS[0] = clo;
                    refS[1] = chi;
                }
            }
        }
    }
    __syncthreads();

    const int wave = t >> 6;
    const int lane = t & 63;
    const int b    = blockIdx.x;
    const int rg   = b >> 2;             // row group (768)
    const int c    = b & 3;              // m chunk (4)
    const int row  = rg * WPB + wave;
    const int mb   = c * MC;

    const float clo = refS[0];
    const float chi = refS[1];
    const float* refB = &refS[10];

    const float* __restrict__ drow = nd + (size_t)row * NN + mb;
    const float* __restrict__ nrow = nm + (size_t)row * NN + mb;

    float dg[OO], sg[OO], corr[OO];
#pragma unroll
    for (int o = 0; o < OO; ++o) { dg[o] = 0.f; sg[o] = 0.f; corr[o] = 0.f; }

    for (int it = 0; it < MC / 256; ++it) {     // 3 iters (ROLLED), 4 m/lane
        const int m0 = it * 256 + lane * 4;
        const float4 dv = *reinterpret_cast<const float4*>(drow + m0);
        const float4 nv = *reinterpret_cast<const float4*>(nrow + m0);
        float4 gv[OO];
#pragma unroll
        for (int o = 0; o < OO; ++o)
            gv[o] = *reinterpret_cast<const float4*>(&gT[o * NN + mb + m0]);

        {
            float gk[OO];
#pragma unroll
            for (int o = 0; o < OO; ++o) gk[o] = gv[o].x;
            accum_one(__fdividef(dv.x, nv.x), clo, chi, gk, dg, sg, corr, KpS, rowsS, refB);
        }
        {
            float gk[OO];
#pragma unroll
            for (int o = 0; o < OO; ++o) gk[o] = gv[o].y;
            accum_one(__fdividef(dv.y, nv.y), clo, chi, gk, dg, sg, corr, KpS, rowsS, refB);
        }
        {
            float gk[OO];
#pragma unroll
            for (int o = 0; o < OO; ++o) gk[o] = gv[o].z;
            accum_one(__fdividef(dv.z, nv.z), clo, chi, gk, dg, sg, corr, KpS, rowsS, refB);
        }
        {
            float gk[OO];
#pragma unroll
            for (int o = 0; o < OO; ++o) gk[o] = gv[o].w;
            accum_one(__fdividef(dv.w, nv.w), clo, chi, gk, dg, sg, corr, KpS, rowsS, refB);
        }
    }

    // val[o] = alpha_ref*dg + beta_ref*sg + corr; wave-reduce; atomic add
    float val[OO];
#pragma unroll
    for (int o = 0; o < OO; ++o)
        val[o] = fmaf(refS[2 + o], dg[o], fmaf(refB[o], sg[o], corr[o]));
#pragma unroll
    for (int o = 0; o < OO; ++o) {
#pragma unroll
        for (int off = 32; off > 0; off >>= 1)
            val[o] += __shfl_down(val[o], off);
    }
    if (lane == 0) {
#pragma unroll
        for (int o = 0; o < OO; ++o)
            atomicAdd(out + (size_t)row * OO + o, val[o]);
    }
}

// ---------------------------------------------------------------------------
// Host launcher — 2 dispatches.
// Inputs: 0:x 1:edge_index(unused) 2:nd 3:nm 4:W1 5:b1 6:W2 7:b2
//         8:rW1 9:rb1 10:rW2 11:rb2
// ---------------------------------------------------------------------------
extern "C" void kernel_launch(void* const* d_in, const int* in_sizes, int n_in,
                              void* d_out, int out_size, void* d_ws, size_t ws_size,
                              hipStream_t stream) {
    const float* x   = (const float*)d_in[0];
    const float* nd  = (const float*)d_in[2];
    const float* nm  = (const float*)d_in[3];
    const float* W1  = (const float*)d_in[4];
    const float* b1  = (const float*)d_in[5];
    const float* W2  = (const float*)d_in[6];
    const float* b2  = (const float*)d_in[7];
    const float* rW1 = (const float*)d_in[8];
    const float* rb1 = (const float*)d_in[9];
    const float* rW2 = (const float*)d_in[10];
    const float* rb2 = (const float*)d_in[11];
    float* out = (float*)d_out;
    float* wsf = (float*)d_ws;

    gnan_g_kernel<<<NN / NPB, 128, 0, stream>>>(x, W1, b1, W2, b2,
                                                wsf + OFF_GT, out);
    gnan_main_kernel<<<(NN / WPB) * SCH, 256, 0, stream>>>(
        nd, nm, wsf + OFF_GT, rW1, rb1, rW2, rb2, out);
}

// Round 10
// 148.736 us; speedup vs baseline: 1.6094x; 1.1739x over previous
//
#include <hip/hip_runtime.h>
#include <hip/hip_bf16.h>
#include <math.h>

// Problem constants: N=3072 nodes, F=128 in-feats, H=16 hidden, O=8 out
#define NN 3072
#define FF 128
#define HH 16
#define OO 8

#define MC   1024              // m-chunk per block
#define NCH  3                 // NN / MC
#define RPB  8                 // rows per block (one per wave), 512 threads

// ws layout (float offsets)
#define OFF_GT   0             // gT[O][N]            24576 floats
#define OFF_KP   24576         // Kp[18] knee bounds (-inf, 16 sorted knees, +inf)
#define OFF_ROWS 24600         // rows[17][16]: alpha[8],beta[8] per interval
#define OFF_REF  24872         // clo, chi, alpha_ref[8], beta_ref[8]
// total 24890 floats = 99560 B

// ---------------------------------------------------------------------------
// Kernel 1: gT[o][n] = sum_f ( sum_h relu(x[n,f]*W1[f,h]+b1[f,h]) * W2[f,h,o]
//                              + b2[f,o] )
// Thread = feature. Weights streamed per-h. First 48 blocks also zero out[]
// (stream order guarantees completion before the main kernel; proven in
// rounds 6-9).
// ---------------------------------------------------------------------------
#define NPB 4

__global__ __launch_bounds__(128) void gnan_g_kernel(
    const float* __restrict__ x,    // [N,F]
    const float* __restrict__ W1,   // [F,H]
    const float* __restrict__ b1,   // [F,H]
    const float* __restrict__ W2,   // [F,H,O]
    const float* __restrict__ b2,   // [F,O]
    float* __restrict__ gT,         // [O][N] in ws
    float* __restrict__ out)        // [N,O] zeroed here
{
    const int f  = threadIdx.x;
    const int n0 = blockIdx.x * NPB;

    {   // zero out[]: NN*OO = 24576 floats = 6144 float4
        const int gid = blockIdx.x * 128 + threadIdx.x;
        if (gid < NN * OO / 4)
            reinterpret_cast<float4*>(out)[gid] = make_float4(0.f, 0.f, 0.f, 0.f);
    }

    float xv[NPB];
#pragma unroll
    for (int ni = 0; ni < NPB; ++ni)
        xv[ni] = x[(size_t)(n0 + ni) * FF + f];

    const float4 b2a = *reinterpret_cast<const float4*>(b2 + f * OO);
    const float4 b2b = *reinterpret_cast<const float4*>(b2 + f * OO + 4);

    float acc[NPB][OO];
#pragma unroll
    for (int ni = 0; ni < NPB; ++ni) {
        acc[ni][0] = b2a.x; acc[ni][1] = b2a.y; acc[ni][2] = b2a.z; acc[ni][3] = b2a.w;
        acc[ni][4] = b2b.x; acc[ni][5] = b2b.y; acc[ni][6] = b2b.z; acc[ni][7] = b2b.w;
    }

    for (int h = 0; h < HH; ++h) {
        const float w1h = W1[f * HH + h];
        const float b1h = b1[f * HH + h];
        const float4 wa = *reinterpret_cast<const float4*>(W2 + (size_t)(f * HH + h) * OO);
        const float4 wb = *reinterpret_cast<const float4*>(W2 + (size_t)(f * HH + h) * OO + 4);
#pragma unroll
        for (int ni = 0; ni < NPB; ++ni) {
            const float a = fmaxf(fmaf(xv[ni], w1h, b1h), 0.f);
            acc[ni][0] = fmaf(a, wa.x, acc[ni][0]);
            acc[ni][1] = fmaf(a, wa.y, acc[ni][1]);
            acc[ni][2] = fmaf(a, wa.z, acc[ni][2]);
            acc[ni][3] = fmaf(a, wa.w, acc[ni][3]);
            acc[ni][4] = fmaf(a, wb.x, acc[ni][4]);
            acc[ni][5] = fmaf(a, wb.y, acc[ni][5]);
            acc[ni][6] = fmaf(a, wb.z, acc[ni][6]);
            acc[ni][7] = fmaf(a, wb.w, acc[ni][7]);
        }
    }

    __shared__ float wsum[2][OO];
    const int lane = threadIdx.x & 63;
    const int wid  = threadIdx.x >> 6;

    for (int ni = 0; ni < NPB; ++ni) {
#pragma unroll
        for (int o = 0; o < OO; ++o) {
#pragma unroll
            for (int off = 32; off > 0; off >>= 1)
                acc[ni][o] += __shfl_down(acc[ni][o], off);
        }
        if (lane == 0) {
#pragma unroll
            for (int o = 0; o < OO; ++o) wsum[wid][o] = acc[ni][o];
        }
        __syncthreads();
        if (threadIdx.x < OO)
            gT[threadIdx.x * NN + (n0 + ni)] = wsum[0][threadIdx.x] + wsum[1][threadIdx.x];
        __syncthreads();
    }
}

// ---------------------------------------------------------------------------
// Kernel 2 (setup): SORT-FREE parallel table build (round-4 version, the
// config measured in the best total run R5=149.9us). One tiny dispatch; no
// LDS, no syncthreads, no serial section.
// ---------------------------------------------------------------------------
__global__ __launch_bounds__(256) void gnan_setup_kernel(
    const float* __restrict__ nd,
    const float* __restrict__ nm,
    const float* __restrict__ rW1,
    const float* __restrict__ rb1,
    const float* __restrict__ rW2,
    const float* __restrict__ rb2,
    float* __restrict__ wsf)
{
    const int t = threadIdx.x;

    float w[HH], b[HH], knee[HH];
#pragma unroll
    for (int h = 0; h < HH; ++h) {
        w[h] = rW1[h];
        b[h] = rb1[h];
        knee[h] = (w[h] != 0.f) ? (-b[h] / w[h]) : INFINITY;
    }

    if (t == 0) {
        wsf[OFF_KP + 0]      = -INFINITY;
        wsf[OFF_KP + HH + 1] =  INFINITY;
    }

    // Kp scatter: thread t<16 places knee_t at its rank.
    if (t < HH) {
        const float kt = knee[0] * 0.f + ((rW1[t] != 0.f) ? (-rb1[t] / rW1[t]) : INFINITY);
        int r = 0;
#pragma unroll
        for (int h2 = 0; h2 < HH; ++h2)
            r += (knee[h2] < kt || (knee[h2] == kt && h2 < t)) ? 1 : 0;
        wsf[OFF_KP + 1 + r] = kt;
    }

    // rows[j][0..7]=alpha, rows[j][8..15]=beta  (136 threads: one (j,o) each)
    if (t < (HH + 1) * OO) {
        const int j = t >> 3, o = t & 7;

        float cAdd = rb2[o];
#pragma unroll
        for (int h = 0; h < HH; ++h)
            if (w[h] == 0.f) cAdd += fmaxf(b[h], 0.f) * rW2[h * OO + o];

        float alpha = 0.f, beta = 0.f;
#pragma unroll
        for (int h = 0; h < HH; ++h) {
            int r = 0;
#pragma unroll
            for (int h2 = 0; h2 < HH; ++h2)
                r += (knee[h2] < knee[h] || (knee[h2] == knee[h] && h2 < h)) ? 1 : 0;
            const bool active = (w[h] > 0.f) ? (r < j)
                              : (w[h] < 0.f ? (r >= j) : false);
            if (active) {
                alpha += w[h] * rW2[h * OO + o];
                beta  += b[h] * rW2[h * OO + o];
            }
        }
        const float betaF = beta + cAdd;
        wsf[OFF_ROWS + j * 16 + o]     = alpha;
        wsf[OFF_ROWS + j * 16 + 8 + o] = betaF;

        // reference interval = interval of d00
        const float d00 = nd[0] / nm[0];
        int j0 = 0;
#pragma unroll
        for (int h = 0; h < HH; ++h) j0 += (d00 >= knee[h]) ? 1 : 0;

        if (j == j0) {
            wsf[OFF_REF + 2 + o]  = alpha;
            wsf[OFF_REF + 10 + o] = betaF;
            if (o == 0) {
                float clo = -INFINITY, chi = INFINITY;
#pragma unroll
                for (int h = 0; h < HH; ++h) {
                    if (d00 >= knee[h]) clo = fmaxf(clo, knee[h]);
                    else                chi = fminf(chi, knee[h]);
                }
                wsf[OFF_REF + 0] = clo;
                wsf[OFF_REF + 1] = chi;
            }
        }
    }
}

// ---------------------------------------------------------------------------
// Kernel 3 (main): out[n,o] += alpha_ref[o]*sum_m d*g + beta_ref[o]*sum_m g
//                              + corrections (rare, exec-masked)
// Round-4/5 configuration (best measured total): block = 512 thr = 8 waves
// = 8 rows x one 1024-m chunk; gs = 32 KB LDS; in-block chunk g-sums;
// atomicAdd combine. Tables read from ws (built once by setup).
// ---------------------------------------------------------------------------
__global__ __launch_bounds__(512) void gnan_main_kernel(
    const float* __restrict__ nd,    // [N,N]
    const float* __restrict__ nm,    // [N,N]
    const float* __restrict__ wsf,   // ws (gT + tables)
    float* __restrict__ out)         // [N,O], zeroed by g-kernel
{
    __shared__ float gs[OO * MC];    // 32 KB
    __shared__ float gsum[OO];       // per-chunk sum of g per o

    const int t  = threadIdx.x;
    const int b  = blockIdx.x;
    const int rg = b / NCH;          // row group
    const int c  = b % NCH;          // m chunk

    {   // stage g chunk: [o][MC] rows, float4 linear copy
        float4*       dst = reinterpret_cast<float4*>(gs);
        const float4* src = reinterpret_cast<const float4*>(wsf + OFF_GT);
        for (int i = t; i < OO * MC / 4; i += 512) {
            const int o  = i >> 8;          // / (MC/4)
            const int mi = i & 255;
            dst[i] = src[o * (NN / 4) + c * (MC / 4) + mi];
        }
    }
    const float clo = wsf[OFF_REF + 0];
    const float chi = wsf[OFF_REF + 1];
    __syncthreads();

    const int wave = t >> 6;
    const int lane = t & 63;

    {   // chunk g-sum: wave w sums gs[w][*] (stride-1 -> 2-way alias, free)
        float s = 0.f;
        for (int i = lane; i < MC; i += 64) s += gs[wave * MC + i];
#pragma unroll
        for (int off = 32; off > 0; off >>= 1) s += __shfl_down(s, off);
        if (lane == 0) gsum[wave] = s;
    }
    __syncthreads();

    const int row = rg * RPB + wave;
    const float* __restrict__ drow = nd + (size_t)row * NN + c * MC;
    const float* __restrict__ nrow = nm + (size_t)row * NN + c * MC;

    float dg[OO], corr[OO];
#pragma unroll
    for (int o = 0; o < OO; ++o) { dg[o] = 0.f; corr[o] = 0.f; }

    for (int it = 0; it < MC / 128; ++it) {     // 8 iters, 2 m per lane
        const int m0 = it * 128 + lane * 2;
        const float2 dv = *reinterpret_cast<const float2*>(drow + m0);
        const float2 nv = *reinterpret_cast<const float2*>(nrow + m0);
        float2 gv[OO];
#pragma unroll
        for (int o = 0; o < OO; ++o)
            gv[o] = *reinterpret_cast<const float2*>(&gs[o * MC + m0]);

#pragma unroll
        for (int k = 0; k < 2; ++k) {
            const float d = __fdividef(k == 0 ? dv.x : dv.y,
                                       k == 0 ? nv.x : nv.y);
            if (d >= clo && d < chi) {          // reference interval (hot)
#pragma unroll
                for (int o = 0; o < OO; ++o) {
                    const float g = (k == 0) ? gv[o].x : gv[o].y;
                    dg[o] = fmaf(d, g, dg[o]);
                }
            } else {                            // rare exact correction
                int j = 0;
#pragma unroll
                for (int p = 0; p < HH; ++p)
                    j += (d >= wsf[OFF_KP + 1 + p]) ? 1 : 0;
#pragma unroll
                for (int o = 0; o < OO; ++o) {
                    const float a  = wsf[OFF_ROWS + j * 16 + o];
                    const float bb = wsf[OFF_ROWS + j * 16 + 8 + o];
                    const float g  = (k == 0) ? gv[o].x : gv[o].y;
                    const float v  = fmaf(a, d, bb) - wsf[OFF_REF + 10 + o];
                    corr[o] = fmaf(v, g, corr[o]);
                }
            }
        }
    }

    // val[o] = alpha_ref[o]*dg[o] + corr[o]; reduce over wave; atomic add
    float val[OO];
#pragma unroll
    for (int o = 0; o < OO; ++o)
        val[o] = fmaf(wsf[OFF_REF + 2 + o], dg[o], corr[o]);
#pragma unroll
    for (int o = 0; o < OO; ++o) {
#pragma unroll
        for (int off = 32; off > 0; off >>= 1)
            val[o] += __shfl_down(val[o], off);
    }
    if (lane == 0) {
#pragma unroll
        for (int o = 0; o < OO; ++o)
            atomicAdd(out + (size_t)row * OO + o,
                      fmaf(wsf[OFF_REF + 10 + o], gsum[o], val[o]));
    }
}

// ---------------------------------------------------------------------------
// Host launcher — 3 dispatches (memset folded into g-kernel; otherwise the
// round-5 measured-best configuration verbatim).
// Inputs: 0:x 1:edge_index(unused) 2:nd 3:nm 4:W1 5:b1 6:W2 7:b2
//         8:rW1 9:rb1 10:rW2 11:rb2
// ---------------------------------------------------------------------------
extern "C" void kernel_launch(void* const* d_in, const int* in_sizes, int n_in,
                              void* d_out, int out_size, void* d_ws, size_t ws_size,
                              hipStream_t stream) {
    const float* x   = (const float*)d_in[0];
    const float* nd  = (const float*)d_in[2];
    const float* nm  = (const float*)d_in[3];
    const float* W1  = (const float*)d_in[4];
    const float* b1  = (const float*)d_in[5];
    const float* W2  = (const float*)d_in[6];
    const float* b2  = (const float*)d_in[7];
    const float* rW1 = (const float*)d_in[8];
    const float* rb1 = (const float*)d_in[9];
    const float* rW2 = (const float*)d_in[10];
    const float* rb2 = (const float*)d_in[11];
    float* out = (float*)d_out;
    float* wsf = (float*)d_ws;

    gnan_g_kernel<<<NN / NPB, 128, 0, stream>>>(x, W1, b1, W2, b2,
                                                wsf + OFF_GT, out);
    gnan_setup_kernel<<<1, 256, 0, stream>>>(nd, nm, rW1, rb1, rW2, rb2, wsf);
    gnan_main_kernel<<<(NN / RPB) * NCH, 512, 0, stream>>>(nd, nm, wsf, out);
}